// Round 1
// baseline (1234.504 us; speedup 1.0000x reference)
//
#include <hip/hip_runtime.h>

#define NUM_TAGS 128
#define NUM_FEATS 500000
#define BB 64
#define TT 512
#define FF 8

// K1: emissions[token][k] = sum_f state_weights[k, feats[token,f]]
// grid = B*T tokens, block = 128 (one thread per tag k).
// feats reads are block-uniform -> scalarized; the 8 gathers per thread are
// independent scattered 4B loads (latency-hidden by 32768 blocks).
__global__ __launch_bounds__(128) void emis_kernel(
    const int* __restrict__ feats, const float* __restrict__ sw,
    float* __restrict__ em) {
  const int token = blockIdx.x;
  const int k = threadIdx.x;
  const int* f = feats + token * FF;
  int f0 = f[0], f1 = f[1], f2 = f[2], f3 = f[3];
  int f4 = f[4], f5 = f[5], f6 = f[6], f7 = f[7];
  const float* row = sw + (size_t)k * NUM_FEATS;
  float s = row[f0] + row[f1] + row[f2] + row[f3]
          + row[f4] + row[f5] + row[f6] + row[f7];
  em[(size_t)token * NUM_TAGS + k] = s;
}

// K2: forward algorithm in PROBABILITY space (threshold is ~2% relative, so
// no logsumexp needed). alphaP_t = (expT^T alphaP_{t-1}) .* expEm_t * 2^-7.
// Deterministic 2^-7 rescale per step keeps alphaP ~O(1); log-correction
// 511*7*ln2 added at the end. expT column j lives in 128 VGPRs per thread;
// alpha broadcast from LDS via float4.
__global__ __launch_bounds__(128, 1) void fwd_kernel(
    const float* __restrict__ em, const int* __restrict__ tags,
    const float* __restrict__ trans, const float* __restrict__ startT,
    const float* __restrict__ endT, float* __restrict__ out) {
  const int b = blockIdx.x;
  const int j = threadIdx.x;
  __shared__ float alpha[NUM_TAGS];
  __shared__ float sred[2];

  float expT[NUM_TAGS];
#pragma unroll
  for (int i = 0; i < NUM_TAGS; ++i)
    expT[i] = __expf(trans[i * NUM_TAGS + j]);   // coalesced per i

  const float* emb = em + (size_t)b * TT * NUM_TAGS;

  alpha[j] = __expf(startT[j] + emb[j]);
  __syncthreads();

  float emv_next = emb[NUM_TAGS + j];
  for (int t = 1; t < TT; ++t) {
    float emv = emv_next;
    if (t + 1 < TT) emv_next = emb[(t + 1) * NUM_TAGS + j];  // prefetch

    float acc = 0.f;
    const float4* a4 = (const float4*)alpha;
#pragma unroll
    for (int i = 0; i < NUM_TAGS / 4; ++i) {
      float4 a = a4[i];                // broadcast ds_read_b128
      acc = fmaf(a.x, expT[4 * i + 0], acc);
      acc = fmaf(a.y, expT[4 * i + 1], acc);
      acc = fmaf(a.z, expT[4 * i + 2], acc);
      acc = fmaf(a.w, expT[4 * i + 3], acc);
    }
    float na = acc * __expf(emv) * 0.0078125f;   // * 2^-7 rescale
    __syncthreads();
    alpha[j] = na;
    __syncthreads();
  }

  // logZ = log(sum_j alphaP[j]*exp(end[j])) + 511*7*ln2
  float val = alpha[j] * __expf(endT[j]);
#pragma unroll
  for (int off = 32; off > 0; off >>= 1) val += __shfl_down(val, off, 64);
  if ((j & 63) == 0) sred[j >> 6] = val;
  __syncthreads();
  float logz = logf(sred[0] + sred[1]) + 511.0f * 7.0f * 0.69314718055994531f;
  __syncthreads();  // before reusing sred

  // gold score: thread j handles t = j, j+128, j+256, j+384
  const int* tb = tags + b * TT;
  float g = 0.f;
#pragma unroll
  for (int c = 0; c < 4; ++c) {
    int t = j + c * 128;
    int tg = tb[t];
    g += emb[t * NUM_TAGS + tg];
    if (t < TT - 1) g += trans[tg * NUM_TAGS + tb[t + 1]];
  }
  if (j == 0) g += startT[tb[0]] + endT[tb[TT - 1]];
#pragma unroll
  for (int off = 32; off > 0; off >>= 1) g += __shfl_down(g, off, 64);
  if ((j & 63) == 0) sred[j >> 6] = g;
  __syncthreads();
  if (j == 0) out[b] = logz - (sred[0] + sred[1]);
}

extern "C" void kernel_launch(void* const* d_in, const int* in_sizes, int n_in,
                              void* d_out, int out_size, void* d_ws, size_t ws_size,
                              hipStream_t stream) {
  const int* feats = (const int*)d_in[0];
  const int* tags = (const int*)d_in[1];
  const float* sw = (const float*)d_in[2];
  const float* trans = (const float*)d_in[3];
  const float* startT = (const float*)d_in[4];
  const float* endT = (const float*)d_in[5];
  float* out = (float*)d_out;
  float* em = (float*)d_ws;  // [B*T][128] fp32 = 16 MB

  emis_kernel<<<BB * TT, 128, 0, stream>>>(feats, sw, em);
  fwd_kernel<<<BB, 128, 0, stream>>>(em, tags, trans, startT, endT, out);
}

// Round 2
// 566.573 us; speedup vs baseline: 2.1789x; 2.1789x over previous
//
#include <hip/hip_runtime.h>

#define NUM_TAGS 128
#define NUM_FEATS 500000
#define BB 64
#define TT 512
#define FF 8

#define SWT_BYTES 256000000ull            // 500000*128*4
#define EM_BYTES  16777216ull             // 64*512*128*4
#define NEED_FULL (SWT_BYTES + EM_BYTES)

// T1: transpose state_weights [128][500000] -> swT [500000][128].
// Tile 32 feats x 128 tags per block; both global phases fully coalesced.
__global__ __launch_bounds__(256) void transpose_kernel(
    const float* __restrict__ sw, float* __restrict__ swT) {
  __shared__ float tile[32][129];
  const int f0 = blockIdx.x * 32;
  const int t = threadIdx.x;
  const int fi = t & 31, kb = t >> 5;          // kb 0..7
#pragma unroll
  for (int it = 0; it < 16; ++it) {
    int k = kb + it * 8;
    tile[fi][k] = sw[(size_t)k * NUM_FEATS + f0 + fi];  // 128B coalesced
  }
  __syncthreads();
  const int k2 = t & 127, fo = t >> 7;         // fo 0..1
#pragma unroll
  for (int it = 0; it < 16; ++it) {
    int f2 = fo + it * 2;
    swT[(size_t)(f0 + f2) * NUM_TAGS + k2] = tile[f2][k2];  // 512B coalesced
  }
}

// K1a (full path): emissions from transposed table — each (token,f) reads a
// contiguous 512B row; thread k handles tag k (coalesced). exp() folded in.
__global__ __launch_bounds__(128) void gather_t_kernel(
    const int* __restrict__ feats, const float* __restrict__ swT,
    float* __restrict__ em_exp) {
  const int token = blockIdx.x;
  const int k = threadIdx.x;
  const int* f = feats + token * FF;
  float s = 0.f;
#pragma unroll
  for (int i = 0; i < FF; ++i) s += swT[(size_t)f[i] * NUM_TAGS + k];
  em_exp[(size_t)token * NUM_TAGS + k] = __expf(s);
}

// K1b (fallback if ws too small): direct strided gather (round-1 style), exp folded.
__global__ __launch_bounds__(128) void gather_f_kernel(
    const int* __restrict__ feats, const float* __restrict__ sw,
    float* __restrict__ em_exp) {
  const int token = blockIdx.x;
  const int k = threadIdx.x;
  const int* f = feats + token * FF;
  const float* row = sw + (size_t)k * NUM_FEATS;
  float s = 0.f;
#pragma unroll
  for (int i = 0; i < FF; ++i) s += row[f[i]];
  em_exp[(size_t)token * NUM_TAGS + k] = __expf(s);
}

// K2: prob-space forward, 512 threads/block (q = tid>>7 splits the 128-dot
// 4 ways -> 32-FMA chains). expT slice: 32 VGPRs/thread. emissions arrive
// pre-exponentiated. 2 barriers/step. Gold emission via __logf(em_exp).
__global__ __launch_bounds__(512, 1) void fwd_kernel(
    const float* __restrict__ em_exp, const int* __restrict__ tags,
    const float* __restrict__ trans, const float* __restrict__ startT,
    const float* __restrict__ endT, float* __restrict__ out) {
  const int b = blockIdx.x;
  const int tid = threadIdx.x;
  const int q = tid >> 7, j = tid & 127;

  __shared__ __align__(16) float alpha[NUM_TAGS];
  __shared__ __align__(16) float partial[NUM_TAGS * 4];
  __shared__ float sred[16];

  float eT[32];
#pragma unroll
  for (int i = 0; i < 32; ++i)
    eT[i] = __expf(trans[(32 * q + i) * NUM_TAGS + j]);  // coalesced

  const float* embx = em_exp + (size_t)b * TT * NUM_TAGS;

  if (q == 0) alpha[j] = __expf(startT[j]) * embx[j];
  __syncthreads();

  float ev_next = embx[NUM_TAGS + j];
  for (int t = 1; t < TT; ++t) {
    float ev = ev_next;
    if (t + 1 < TT) ev_next = embx[(t + 1) * NUM_TAGS + j];  // prefetch

    const float4* a4 = (const float4*)alpha + q * 8;
    float acc = 0.f, acc2 = 0.f;
#pragma unroll
    for (int i = 0; i < 8; ++i) {
      float4 a = a4[i];               // wave-uniform address: LDS broadcast
      acc  = fmaf(a.x, eT[4 * i + 0], acc);
      acc2 = fmaf(a.y, eT[4 * i + 1], acc2);
      acc  = fmaf(a.z, eT[4 * i + 2], acc);
      acc2 = fmaf(a.w, eT[4 * i + 3], acc2);
    }
    partial[j * 4 + q] = acc + acc2;
    __syncthreads();
    float4 p = *(const float4*)&partial[j * 4];
    if (q == 0) alpha[j] = (p.x + p.y + p.z + p.w) * ev * 0.0078125f;  // *2^-7
    __syncthreads();
  }

  // logZ (q0 threads, 2 waves) -> sred[0..1]
  if (q == 0) {
    float val = alpha[j] * __expf(endT[j]);
#pragma unroll
    for (int off = 32; off > 0; off >>= 1) val += __shfl_down(val, off, 64);
    if ((j & 63) == 0) sred[j >> 6] = val;
  }

  // gold: thread tid handles t = tid -> sred[8..15]
  const int* tb = tags + b * TT;
  const int t = tid;
  const int tg = tb[t];
  float g = __logf(embx[t * NUM_TAGS + tg]);
  if (t < TT - 1) g += trans[tg * NUM_TAGS + tb[t + 1]];
  if (t == 0) g += startT[tb[0]] + endT[tb[TT - 1]];
#pragma unroll
  for (int off = 32; off > 0; off >>= 1) g += __shfl_down(g, off, 64);
  if ((tid & 63) == 0) sred[8 + (tid >> 6)] = g;
  __syncthreads();

  if (tid == 0) {
    float logz = __logf(sred[0] + sred[1]) + 511.0f * 7.0f * 0.69314718055994531f;
    float gs = 0.f;
#pragma unroll
    for (int i = 0; i < 8; ++i) gs += sred[8 + i];
    out[b] = logz - gs;
  }
}

extern "C" void kernel_launch(void* const* d_in, const int* in_sizes, int n_in,
                              void* d_out, int out_size, void* d_ws, size_t ws_size,
                              hipStream_t stream) {
  const int* feats = (const int*)d_in[0];
  const int* tags = (const int*)d_in[1];
  const float* sw = (const float*)d_in[2];
  const float* trans = (const float*)d_in[3];
  const float* startT = (const float*)d_in[4];
  const float* endT = (const float*)d_in[5];
  float* out = (float*)d_out;

  if (ws_size >= NEED_FULL) {
    float* swT = (float*)d_ws;
    float* em_exp = (float*)((char*)d_ws + SWT_BYTES);
    transpose_kernel<<<NUM_FEATS / 32, 256, 0, stream>>>(sw, swT);
    gather_t_kernel<<<BB * TT, 128, 0, stream>>>(feats, swT, em_exp);
    fwd_kernel<<<BB, 512, 0, stream>>>(em_exp, tags, trans, startT, endT, out);
  } else {
    float* em_exp = (float*)d_ws;
    gather_f_kernel<<<BB * TT, 128, 0, stream>>>(feats, sw, em_exp);
    fwd_kernel<<<BB, 512, 0, stream>>>(em_exp, tags, trans, startT, endT, out);
  }
}